// Round 1
// baseline (735.135 us; speedup 1.0000x reference)
//
#include <hip/hip_runtime.h>
#include <math.h>

#define N_NODES 100000

// ---------------- degree ----------------
__global__ void k_deg(const int* __restrict__ dst, int E, int* __restrict__ deg) {
    int tid = blockIdx.x * blockDim.x + threadIdx.x;
    if (tid < E) atomicAdd(&deg[dst[tid]], 1);
}

__global__ void k_dinv(const int* __restrict__ deg, float* __restrict__ dinv, int N) {
    int i = blockIdx.x * blockDim.x + threadIdx.x;
    if (i < N) dinv[i] = rsqrtf((float)(deg[i] + 1));  // +1 self-loop
}

// ---------------- conv1 linear: h1 = (x @ W1) * dinv ; acc1 = h1 (self-loop term) ----
__global__ void k_lin1(const float* __restrict__ x, const float* __restrict__ W1,
                       const float* __restrict__ dinv,
                       float* __restrict__ h1, float* __restrict__ acc1, int N) {
    int i = blockIdx.x * blockDim.x + threadIdx.x;
    if (i >= N) return;
    float x0 = x[3*i], x1 = x[3*i+1], x2 = x[3*i+2];
    float di = dinv[i];
    #pragma unroll
    for (int j = 0; j < 16; ++j) {
        float v = (x0 * W1[j] + x1 * W1[16 + j] + x2 * W1[32 + j]) * di;
        h1[16*i + j] = v;
        acc1[16*i + j] = v;
    }
}

// one thread per (edge, feature j<16)
__global__ void k_scatter16(const int* __restrict__ src, const int* __restrict__ dst,
                            const float* __restrict__ h, float* __restrict__ acc, int E) {
    int tid = blockIdx.x * blockDim.x + threadIdx.x;  // E*16 = 51.2M < 2^31
    if (tid >= E * 16) return;
    int e = tid >> 4, j = tid & 15;
    int s = src[e], d = dst[e];
    atomicAdd(&acc[16*d + j], h[16*s + j]);
}

// conv1 finish (+b1, relu) fused with conv2 linear: h2 = (relu(out1) @ W2) * dinv
__global__ void k_c1fin_c2lin(const float* __restrict__ acc1, const float* __restrict__ b1,
                              const float* __restrict__ W2, const float* __restrict__ dinv,
                              float* __restrict__ h2, float* __restrict__ acc2, int N) {
    int i = blockIdx.x * blockDim.x + threadIdx.x;
    if (i >= N) return;
    float di = dinv[i];
    float o0 = 0.f, o1 = 0.f, o2 = 0.f;
    #pragma unroll
    for (int j = 0; j < 16; ++j) {
        float t = fmaxf(acc1[16*i + j] * di + b1[j], 0.f);
        o0 += t * W2[3*j + 0];
        o1 += t * W2[3*j + 1];
        o2 += t * W2[3*j + 2];
    }
    o0 *= di; o1 *= di; o2 *= di;
    h2[3*i] = o0;  h2[3*i+1] = o1;  h2[3*i+2] = o2;
    acc2[3*i] = o0; acc2[3*i+1] = o1; acc2[3*i+2] = o2;
}

// one thread per (edge, lane j<4), j==3 idle — keeps pow2 indexing
__global__ void k_scatter3(const int* __restrict__ src, const int* __restrict__ dst,
                           const float* __restrict__ h, float* __restrict__ acc, int E) {
    int tid = blockIdx.x * blockDim.x + threadIdx.x;  // E*4 = 12.8M
    if (tid >= E * 4) return;
    int e = tid >> 2, j = tid & 3;
    if (j == 3) return;
    int s = src[e], d = dst[e];
    atomicAdd(&acc[3*d + j], h[3*s + j]);
}

// conv2 finish + L2-normalize + write embed_1 + conv3 linear
__global__ void k_c2fin_norm_c3lin(const float* __restrict__ acc2, const float* __restrict__ b2,
                                   const float* __restrict__ W3, const float* __restrict__ dinv,
                                   float* __restrict__ embed_out,
                                   float* __restrict__ h3, float* __restrict__ acc3, int N) {
    int i = blockIdx.x * blockDim.x + threadIdx.x;
    if (i >= N) return;
    float di = dinv[i];
    float t0 = acc2[3*i]   * di + b2[0];
    float t1 = acc2[3*i+1] * di + b2[1];
    float t2 = acc2[3*i+2] * di + b2[2];
    float nrm = fmaxf(sqrtf(t0*t0 + t1*t1 + t2*t2), 1e-12f);
    float inv = 1.0f / nrm;
    float e0 = t0*inv, e1 = t1*inv, e2 = t2*inv;
    embed_out[3*i] = e0; embed_out[3*i+1] = e1; embed_out[3*i+2] = e2;
    float v0 = (e0*W3[0] + e1*W3[3] + e2*W3[6]) * di;
    float v1 = (e0*W3[1] + e1*W3[4] + e2*W3[7]) * di;
    float v2 = (e0*W3[2] + e1*W3[5] + e2*W3[8]) * di;
    h3[3*i] = v0;  h3[3*i+1] = v1;  h3[3*i+2] = v2;
    acc3[3*i] = v0; acc3[3*i+1] = v1; acc3[3*i+2] = v2;
}

// conv3 finish + project (Wp,bp) + write h + global sum for mean-pool
__global__ void k_c3fin_proj(const float* __restrict__ acc3, const float* __restrict__ b3,
                             const float* __restrict__ Wp, const float* __restrict__ bp,
                             const float* __restrict__ dinv,
                             float* __restrict__ hout, float* __restrict__ gsum, int N) {
    int i = blockIdx.x * blockDim.x + threadIdx.x;
    float p0 = 0.f, p1 = 0.f, p2 = 0.f;
    if (i < N) {
        float di = dinv[i];
        float t0 = acc3[3*i]   * di + b3[0];
        float t1 = acc3[3*i+1] * di + b3[1];
        float t2 = acc3[3*i+2] * di + b3[2];
        p0 = t0*Wp[0] + t1*Wp[3] + t2*Wp[6] + bp[0];
        p1 = t0*Wp[1] + t1*Wp[4] + t2*Wp[7] + bp[1];
        p2 = t0*Wp[2] + t1*Wp[5] + t2*Wp[8] + bp[2];
        hout[3*i] = p0; hout[3*i+1] = p1; hout[3*i+2] = p2;
    }
    // wave-64 reduce, then one atomic per wave per feature
    #pragma unroll
    for (int off = 32; off > 0; off >>= 1) {
        p0 += __shfl_down(p0, off);
        p1 += __shfl_down(p1, off);
        p2 += __shfl_down(p2, off);
    }
    if ((threadIdx.x & 63) == 0) {
        atomicAdd(&gsum[0], p0);
        atomicAdd(&gsum[1], p1);
        atomicAdd(&gsum[2], p2);
    }
}

// mean, logits, log_softmax -> out[0..10)
__global__ void k_head(const float* __restrict__ gsum, const float* __restrict__ Wl,
                       const float* __restrict__ bl, float* __restrict__ out, int N) {
    if (blockIdx.x != 0 || threadIdx.x != 0) return;
    float p0 = gsum[0] / (float)N, p1 = gsum[1] / (float)N, p2 = gsum[2] / (float)N;
    float l[10];
    float m = -1e30f;
    #pragma unroll
    for (int j = 0; j < 10; ++j) {
        l[j] = p0 * Wl[j] + p1 * Wl[10 + j] + p2 * Wl[20 + j] + bl[j];
        m = fmaxf(m, l[j]);
    }
    float s = 0.f;
    #pragma unroll
    for (int j = 0; j < 10; ++j) s += expf(l[j] - m);
    float lse = logf(s) + m;
    #pragma unroll
    for (int j = 0; j < 10; ++j) out[j] = l[j] - lse;
}

extern "C" void kernel_launch(void* const* d_in, const int* in_sizes, int n_in,
                              void* d_out, int out_size, void* d_ws, size_t ws_size,
                              hipStream_t stream) {
    const int N = N_NODES;
    const float* x  = (const float*)d_in[0];
    const int*   ei = (const int*)d_in[1];
    const int    E  = in_sizes[1] / 2;
    const int* src = ei;
    const int* dst = ei + E;
    const float* W1 = (const float*)d_in[2];
    const float* b1 = (const float*)d_in[3];
    const float* W2 = (const float*)d_in[4];
    const float* b2 = (const float*)d_in[5];
    const float* W3 = (const float*)d_in[6];
    const float* b3 = (const float*)d_in[7];
    const float* Wp = (const float*)d_in[8];
    const float* bp = (const float*)d_in[9];
    const float* Wl = (const float*)d_in[10];
    const float* bl = (const float*)d_in[11];

    float* out     = (float*)d_out;
    float* h_out   = out + 10;              // [N,3] projected h
    float* emb_out = out + 10 + 3 * N;      // [N,3] embed_1

    // workspace layout (floats): [0,N) deg(int) | [N,2N) dinv |
    // [2N,18N) hA | [18N,34N) hB | [34N,34N+3) gsum
    float* W = (float*)d_ws;
    int*   deg  = (int*)W;
    float* dinv = W + N;
    float* hA   = W + 2 * N;     // 16N scratch
    float* hB   = W + 18 * N;    // 16N scratch
    float* gsum = W + 34 * N;    // 3 floats

    // conv1 buffers: h1 = hA (16N), acc1 = hB (16N)
    // conv2 buffers (inside hA after conv1's h1 is dead):
    float* h2   = hA;            // 3N
    float* acc2 = hA + 3 * N;    // 3N
    // conv3 buffers:
    float* h3   = hA + 6 * N;    // 3N
    float* acc3 = hA + 9 * N;    // 3N

    hipMemsetAsync(deg, 0, N * sizeof(int), stream);
    hipMemsetAsync(gsum, 0, 3 * sizeof(float), stream);

    const int B = 256;
    int gE   = (E + B - 1) / B;
    int gN   = (N + B - 1) / B;
    int gE16 = (E * 16 + B - 1) / B;
    int gE4  = (E * 4 + B - 1) / B;

    k_deg<<<gE, B, 0, stream>>>(dst, E, deg);
    k_dinv<<<gN, B, 0, stream>>>(deg, dinv, N);

    // conv1
    k_lin1<<<gN, B, 0, stream>>>(x, W1, dinv, hA, hB, N);
    k_scatter16<<<gE16, B, 0, stream>>>(src, dst, hA, hB, E);
    k_c1fin_c2lin<<<gN, B, 0, stream>>>(hB, b1, W2, dinv, h2, acc2, N);

    // conv2
    k_scatter3<<<gE4, B, 0, stream>>>(src, dst, h2, acc2, E);
    k_c2fin_norm_c3lin<<<gN, B, 0, stream>>>(acc2, b2, W3, dinv, emb_out, h3, acc3, N);

    // conv3
    k_scatter3<<<gE4, B, 0, stream>>>(src, dst, h3, acc3, E);
    k_c3fin_proj<<<gN, B, 0, stream>>>(acc3, b3, Wp, bp, dinv, h_out, gsum, N);

    // head
    k_head<<<1, 64, 0, stream>>>(gsum, Wl, bl, out, N);
}

// Round 2
// 565.862 us; speedup vs baseline: 1.2991x; 1.2991x over previous
//
#include <hip/hip_runtime.h>
#include <math.h>

#define N_NODES 100000
#define SCAN_T 1024

// ---- pass 1a (rank path): deg histogram, also record per-edge rank within its dst bucket
__global__ void k_rank(const int* __restrict__ dst, int E,
                       int* __restrict__ deg, int* __restrict__ rank) {
    int e = blockIdx.x * blockDim.x + threadIdx.x;
    if (e < E) rank[e] = atomicAdd(&deg[dst[e]], 1);
}

// ---- pass 1b (cursor path): deg histogram only
__global__ void k_deg(const int* __restrict__ dst, int E, int* __restrict__ deg) {
    int e = blockIdx.x * blockDim.x + threadIdx.x;
    if (e < E) atomicAdd(&deg[dst[e]], 1);
}

// ---- pass 2: single-block exclusive scan of deg -> offs, plus dinv = rsqrt(deg+1)
__global__ void k_scan(const int* __restrict__ deg, int* __restrict__ offs,
                       float* __restrict__ dinv, int N) {
    __shared__ int part[SCAN_T];
    int t = threadIdx.x;
    int chunk = (N + SCAN_T - 1) / SCAN_T;
    int lo = t * chunk;
    int hi = lo + chunk; if (hi > N) hi = N;
    int s = 0;
    for (int i = lo; i < hi; ++i) s += deg[i];
    part[t] = s;
    __syncthreads();
    for (int off = 1; off < SCAN_T; off <<= 1) {
        int v = (t >= off) ? part[t - off] : 0;
        __syncthreads();
        part[t] += v;
        __syncthreads();
    }
    int excl = (t == 0) ? 0 : part[t - 1];
    for (int i = lo; i < hi; ++i) {
        int d = deg[i];
        offs[i] = excl;
        excl += d;
        dinv[i] = rsqrtf((float)(d + 1));  // +1 self-loop
    }
    if (t == SCAN_T - 1) offs[N] = part[SCAN_T - 1];
}

// ---- pass 3: fill CSR col array
__global__ void k_fill_rank(const int* __restrict__ src, const int* __restrict__ dst,
                            const int* __restrict__ rank, const int* __restrict__ offs,
                            int* __restrict__ col, int E) {
    int e = blockIdx.x * blockDim.x + threadIdx.x;
    if (e >= E) return;
    col[offs[dst[e]] + rank[e]] = src[e];
}

__global__ void k_fill_cur(const int* __restrict__ src, const int* __restrict__ dst,
                           const int* __restrict__ offs, int* __restrict__ cur,
                           int* __restrict__ col, int E) {
    int e = blockIdx.x * blockDim.x + threadIdx.x;
    if (e >= E) return;
    int d = dst[e];
    col[offs[d] + atomicAdd(&cur[d], 1)] = src[e];
}

// ---- prescale conv1 input: xp = x * dinv
__global__ void k_prescale(const float* __restrict__ x, const float* __restrict__ dinv,
                           float* __restrict__ xp, int N) {
    int i = blockIdx.x * blockDim.x + threadIdx.x;
    if (i >= N) return;
    float di = dinv[i];
    xp[3*i]   = x[3*i]   * di;
    xp[3*i+1] = x[3*i+1] * di;
    xp[3*i+2] = x[3*i+2] * di;
}

// ---- conv1: gather xp, epilogue = (g@W1+b1).relu @ W2 * dinv -> h2p [N,3]
__global__ void k_conv1(const int* __restrict__ offs, const int* __restrict__ col,
                        const float* __restrict__ xp, const float* __restrict__ dinv,
                        const float* __restrict__ W1, const float* __restrict__ b1,
                        const float* __restrict__ W2,
                        float* __restrict__ h2p, int N) {
    int i = blockIdx.x * blockDim.x + threadIdx.x;
    if (i >= N) return;
    float s0 = xp[3*i], s1 = xp[3*i+1], s2 = xp[3*i+2];  // self-loop term
    int beg = offs[i], end = offs[i+1];
    for (int k = beg; k < end; ++k) {
        int s = col[k];
        s0 += xp[3*s]; s1 += xp[3*s+1]; s2 += xp[3*s+2];
    }
    float di = dinv[i];
    float g0 = s0 * di, g1 = s1 * di, g2 = s2 * di;   // (Âx)[i]
    float o0 = 0.f, o1 = 0.f, o2 = 0.f;
    #pragma unroll
    for (int j = 0; j < 16; ++j) {
        float t = fmaxf(g0 * W1[j] + g1 * W1[16 + j] + g2 * W1[32 + j] + b1[j], 0.f);
        o0 += t * W2[3*j + 0];
        o1 += t * W2[3*j + 1];
        o2 += t * W2[3*j + 2];
    }
    h2p[3*i] = o0 * di; h2p[3*i+1] = o1 * di; h2p[3*i+2] = o2 * di;
}

// ---- conv2: gather h2p, epilogue = +b2, L2-normalize -> embed_out; (emb@W3)*dinv -> h3p
__global__ void k_conv2(const int* __restrict__ offs, const int* __restrict__ col,
                        const float* __restrict__ h2p, const float* __restrict__ dinv,
                        const float* __restrict__ b2, const float* __restrict__ W3,
                        float* __restrict__ embed_out, float* __restrict__ h3p, int N) {
    int i = blockIdx.x * blockDim.x + threadIdx.x;
    if (i >= N) return;
    float s0 = h2p[3*i], s1 = h2p[3*i+1], s2 = h2p[3*i+2];
    int beg = offs[i], end = offs[i+1];
    for (int k = beg; k < end; ++k) {
        int s = col[k];
        s0 += h2p[3*s]; s1 += h2p[3*s+1]; s2 += h2p[3*s+2];
    }
    float di = dinv[i];
    float t0 = s0 * di + b2[0];
    float t1 = s1 * di + b2[1];
    float t2 = s2 * di + b2[2];
    float inv = 1.0f / fmaxf(sqrtf(t0*t0 + t1*t1 + t2*t2), 1e-12f);
    float e0 = t0*inv, e1 = t1*inv, e2 = t2*inv;
    embed_out[3*i] = e0; embed_out[3*i+1] = e1; embed_out[3*i+2] = e2;
    h3p[3*i]   = (e0*W3[0] + e1*W3[3] + e2*W3[6]) * di;
    h3p[3*i+1] = (e0*W3[1] + e1*W3[4] + e2*W3[7]) * di;
    h3p[3*i+2] = (e0*W3[2] + e1*W3[5] + e2*W3[8]) * di;
}

// ---- conv3: gather h3p, epilogue = +b3, @Wp+bp -> h_out; wave-reduce -> gsum
__global__ void k_conv3(const int* __restrict__ offs, const int* __restrict__ col,
                        const float* __restrict__ h3p, const float* __restrict__ dinv,
                        const float* __restrict__ b3, const float* __restrict__ Wp,
                        const float* __restrict__ bp,
                        float* __restrict__ hout, float* __restrict__ gsum, int N) {
    int i = blockIdx.x * blockDim.x + threadIdx.x;
    float p0 = 0.f, p1 = 0.f, p2 = 0.f;
    if (i < N) {
        float s0 = h3p[3*i], s1 = h3p[3*i+1], s2 = h3p[3*i+2];
        int beg = offs[i], end = offs[i+1];
        for (int k = beg; k < end; ++k) {
            int s = col[k];
            s0 += h3p[3*s]; s1 += h3p[3*s+1]; s2 += h3p[3*s+2];
        }
        float di = dinv[i];
        float t0 = s0 * di + b3[0];
        float t1 = s1 * di + b3[1];
        float t2 = s2 * di + b3[2];
        p0 = t0*Wp[0] + t1*Wp[3] + t2*Wp[6] + bp[0];
        p1 = t0*Wp[1] + t1*Wp[4] + t2*Wp[7] + bp[1];
        p2 = t0*Wp[2] + t1*Wp[5] + t2*Wp[8] + bp[2];
        hout[3*i] = p0; hout[3*i+1] = p1; hout[3*i+2] = p2;
    }
    #pragma unroll
    for (int off = 32; off > 0; off >>= 1) {
        p0 += __shfl_down(p0, off);
        p1 += __shfl_down(p1, off);
        p2 += __shfl_down(p2, off);
    }
    if ((threadIdx.x & 63) == 0) {
        atomicAdd(&gsum[0], p0);
        atomicAdd(&gsum[1], p1);
        atomicAdd(&gsum[2], p2);
    }
}

// ---- head: mean, logits, log_softmax
__global__ void k_head(const float* __restrict__ gsum, const float* __restrict__ Wl,
                       const float* __restrict__ bl, float* __restrict__ out, int N) {
    if (blockIdx.x != 0 || threadIdx.x != 0) return;
    float p0 = gsum[0] / (float)N, p1 = gsum[1] / (float)N, p2 = gsum[2] / (float)N;
    float l[10];
    float m = -1e30f;
    #pragma unroll
    for (int j = 0; j < 10; ++j) {
        l[j] = p0 * Wl[j] + p1 * Wl[10 + j] + p2 * Wl[20 + j] + bl[j];
        m = fmaxf(m, l[j]);
    }
    float s = 0.f;
    #pragma unroll
    for (int j = 0; j < 10; ++j) s += expf(l[j] - m);
    float lse = logf(s) + m;
    #pragma unroll
    for (int j = 0; j < 10; ++j) out[j] = l[j] - lse;
}

extern "C" void kernel_launch(void* const* d_in, const int* in_sizes, int n_in,
                              void* d_out, int out_size, void* d_ws, size_t ws_size,
                              hipStream_t stream) {
    const int N = N_NODES;
    const float* x  = (const float*)d_in[0];
    const int*   ei = (const int*)d_in[1];
    const int    E  = in_sizes[1] / 2;
    const int* src = ei;
    const int* dst = ei + E;
    const float* W1 = (const float*)d_in[2];
    const float* b1 = (const float*)d_in[3];
    const float* W2 = (const float*)d_in[4];
    const float* b2 = (const float*)d_in[5];
    const float* W3 = (const float*)d_in[6];
    const float* b3 = (const float*)d_in[7];
    const float* Wp = (const float*)d_in[8];
    const float* bp = (const float*)d_in[9];
    const float* Wl = (const float*)d_in[10];
    const float* bl = (const float*)d_in[11];

    float* out     = (float*)d_out;
    float* h_out   = out + 10;              // [N,3]
    float* emb_out = out + 10 + 3 * N;      // [N,3]

    // ---- workspace layout (4-byte units) ----
    // common: col[E] | deg[N] | offs[N+1] | dinv[N] | bufA[3N] | bufB[3N] | gsum[4]
    // rank path adds rank[E]; cursor path adds cur[N].
    char* W = (char*)d_ws;
    size_t off = 0;
    auto alloc = [&](size_t elems) { void* p = W + off; off += elems * 4; return p; };

    int*   col  = (int*)alloc((size_t)E);
    int*   deg  = (int*)alloc(N);
    int*   offs = (int*)alloc(N + 1);
    float* dinv = (float*)alloc(N);
    float* bufA = (float*)alloc(3 * N);
    float* bufB = (float*)alloc(3 * N);
    float* gsum = (float*)alloc(4);
    size_t base_bytes = off;
    size_t rank_bytes = base_bytes + (size_t)E * 4;
    bool use_rank = (ws_size >= rank_bytes);
    int* rank = (int*)(W + base_bytes);              // rank path
    int* cur  = (int*)(W + base_bytes);              // cursor path (N ints)

    hipMemsetAsync(deg, 0, N * sizeof(int), stream);
    hipMemsetAsync(gsum, 0, 4 * sizeof(float), stream);
    if (!use_rank) hipMemsetAsync(cur, 0, N * sizeof(int), stream);

    const int B = 256;
    int gE = (E + B - 1) / B;
    int gN = (N + B - 1) / B;

    // CSR build
    if (use_rank) {
        k_rank<<<gE, B, 0, stream>>>(dst, E, deg, rank);
        k_scan<<<1, SCAN_T, 0, stream>>>(deg, offs, dinv, N);
        k_fill_rank<<<gE, B, 0, stream>>>(src, dst, rank, offs, col, E);
    } else {
        k_deg<<<gE, B, 0, stream>>>(dst, E, deg);
        k_scan<<<1, SCAN_T, 0, stream>>>(deg, offs, dinv, N);
        k_fill_cur<<<gE, B, 0, stream>>>(src, dst, offs, cur, col, E);
    }

    // convs (all 3-wide thanks to Â(xW) = (Âx)W)
    k_prescale<<<gN, B, 0, stream>>>(x, dinv, bufA, N);
    k_conv1<<<gN, B, 0, stream>>>(offs, col, bufA, dinv, W1, b1, W2, bufB, N);
    k_conv2<<<gN, B, 0, stream>>>(offs, col, bufB, dinv, b2, W3, emb_out, bufA, N);
    k_conv3<<<gN, B, 0, stream>>>(offs, col, bufA, dinv, b3, Wp, bp, h_out, gsum, N);

    k_head<<<1, 64, 0, stream>>>(gsum, Wl, bl, out, N);
}

// Round 3
// 352.514 us; speedup vs baseline: 2.0854x; 1.6052x over previous
//
#include <hip/hip_runtime.h>
#include <math.h>

#define N_NODES 100000

// ---- pass 1a (rank path): deg histogram, also record per-edge rank within its dst bucket
__global__ void k_rank(const int* __restrict__ dst, int E,
                       int* __restrict__ deg, int* __restrict__ rank) {
    int e = blockIdx.x * blockDim.x + threadIdx.x;
    if (e < E) rank[e] = atomicAdd(&deg[dst[e]], 1);
}

// ---- pass 1b (cursor path): deg histogram only
__global__ void k_deg(const int* __restrict__ dst, int E, int* __restrict__ deg) {
    int e = blockIdx.x * blockDim.x + threadIdx.x;
    if (e < E) atomicAdd(&deg[dst[e]], 1);
}

// ---- multi-block exclusive scan of deg -> offs (3 passes), plus dinv = rsqrt(deg+1)
__global__ void k_scan1(const int* __restrict__ deg, int* __restrict__ offs,
                        float* __restrict__ dinv, int* __restrict__ part, int N) {
    __shared__ int sh[256];
    int i = blockIdx.x * 256 + threadIdx.x;
    int t = threadIdx.x;
    int v = (i < N) ? deg[i] : 0;
    sh[t] = v;
    __syncthreads();
    // Hillis-Steele inclusive scan
    #pragma unroll
    for (int off = 1; off < 256; off <<= 1) {
        int u = (t >= off) ? sh[t - off] : 0;
        __syncthreads();
        sh[t] += u;
        __syncthreads();
    }
    if (i < N) {
        offs[i] = sh[t] - v;          // exclusive within block
        dinv[i] = rsqrtf((float)(v + 1));
    }
    if (t == 255) part[blockIdx.x] = sh[255];
}

__global__ void k_scan2(int* __restrict__ part, int* __restrict__ offs, int nb, int N) {
    __shared__ int sh[1024];
    int t = threadIdx.x;
    int v = (t < nb) ? part[t] : 0;
    sh[t] = v;
    __syncthreads();
    #pragma unroll
    for (int off = 1; off < 1024; off <<= 1) {
        int u = (t >= off) ? sh[t - off] : 0;
        __syncthreads();
        sh[t] += u;
        __syncthreads();
    }
    if (t < nb) part[t] = sh[t] - v;  // exclusive block base
    if (t == 1023) offs[N] = sh[1023];
}

__global__ void k_scan3(int* __restrict__ offs, const int* __restrict__ part, int N) {
    int i = blockIdx.x * 256 + threadIdx.x;
    if (i < N) offs[i] += part[blockIdx.x];
}

// ---- pass 3: fill CSR col array
__global__ void k_fill_rank(const int* __restrict__ src, const int* __restrict__ dst,
                            const int* __restrict__ rank, const int* __restrict__ offs,
                            int* __restrict__ col, int E) {
    int e = blockIdx.x * blockDim.x + threadIdx.x;
    if (e >= E) return;
    col[offs[dst[e]] + rank[e]] = src[e];
}

__global__ void k_fill_cur(const int* __restrict__ src, const int* __restrict__ dst,
                           const int* __restrict__ offs, int* __restrict__ cur,
                           int* __restrict__ col, int E) {
    int e = blockIdx.x * blockDim.x + threadIdx.x;
    if (e >= E) return;
    int d = dst[e];
    col[offs[d] + atomicAdd(&cur[d], 1)] = src[e];
}

// ---- prescale conv1 input: xp = x * dinv
__global__ void k_prescale(const float* __restrict__ x, const float* __restrict__ dinv,
                           float* __restrict__ xp, int N) {
    int i = blockIdx.x * blockDim.x + threadIdx.x;
    if (i >= N) return;
    float di = dinv[i];
    xp[3*i]   = x[3*i]   * di;
    xp[3*i+1] = x[3*i+1] * di;
    xp[3*i+2] = x[3*i+2] * di;
}

// ---- conv1: gather xp, epilogue = (g@W1+b1).relu @ W2 * dinv -> h2p [N,3]
__global__ void k_conv1(const int* __restrict__ offs, const int* __restrict__ col,
                        const float* __restrict__ xp, const float* __restrict__ dinv,
                        const float* __restrict__ W1, const float* __restrict__ b1,
                        const float* __restrict__ W2,
                        float* __restrict__ h2p, int N) {
    int i = blockIdx.x * blockDim.x + threadIdx.x;
    if (i >= N) return;
    float s0 = xp[3*i], s1 = xp[3*i+1], s2 = xp[3*i+2];  // self-loop term
    int beg = offs[i], end = offs[i+1];
    for (int k = beg; k < end; ++k) {
        int s = col[k];
        s0 += xp[3*s]; s1 += xp[3*s+1]; s2 += xp[3*s+2];
    }
    float di = dinv[i];
    float g0 = s0 * di, g1 = s1 * di, g2 = s2 * di;   // (Âx)[i]
    float o0 = 0.f, o1 = 0.f, o2 = 0.f;
    #pragma unroll
    for (int j = 0; j < 16; ++j) {
        float t = fmaxf(g0 * W1[j] + g1 * W1[16 + j] + g2 * W1[32 + j] + b1[j], 0.f);
        o0 += t * W2[3*j + 0];
        o1 += t * W2[3*j + 1];
        o2 += t * W2[3*j + 2];
    }
    h2p[3*i] = o0 * di; h2p[3*i+1] = o1 * di; h2p[3*i+2] = o2 * di;
}

// ---- conv2: gather h2p, epilogue = +b2, L2-normalize -> embed_out; (emb@W3)*dinv -> h3p
__global__ void k_conv2(const int* __restrict__ offs, const int* __restrict__ col,
                        const float* __restrict__ h2p, const float* __restrict__ dinv,
                        const float* __restrict__ b2, const float* __restrict__ W3,
                        float* __restrict__ embed_out, float* __restrict__ h3p, int N) {
    int i = blockIdx.x * blockDim.x + threadIdx.x;
    if (i >= N) return;
    float s0 = h2p[3*i], s1 = h2p[3*i+1], s2 = h2p[3*i+2];
    int beg = offs[i], end = offs[i+1];
    for (int k = beg; k < end; ++k) {
        int s = col[k];
        s0 += h2p[3*s]; s1 += h2p[3*s+1]; s2 += h2p[3*s+2];
    }
    float di = dinv[i];
    float t0 = s0 * di + b2[0];
    float t1 = s1 * di + b2[1];
    float t2 = s2 * di + b2[2];
    float inv = 1.0f / fmaxf(sqrtf(t0*t0 + t1*t1 + t2*t2), 1e-12f);
    float e0 = t0*inv, e1 = t1*inv, e2 = t2*inv;
    embed_out[3*i] = e0; embed_out[3*i+1] = e1; embed_out[3*i+2] = e2;
    h3p[3*i]   = (e0*W3[0] + e1*W3[3] + e2*W3[6]) * di;
    h3p[3*i+1] = (e0*W3[1] + e1*W3[4] + e2*W3[7]) * di;
    h3p[3*i+2] = (e0*W3[2] + e1*W3[5] + e2*W3[8]) * di;
}

// ---- conv3: gather h3p, epilogue = +b3, @Wp+bp -> h_out; wave-reduce -> gsum
__global__ void k_conv3(const int* __restrict__ offs, const int* __restrict__ col,
                        const float* __restrict__ h3p, const float* __restrict__ dinv,
                        const float* __restrict__ b3, const float* __restrict__ Wp,
                        const float* __restrict__ bp,
                        float* __restrict__ hout, float* __restrict__ gsum, int N) {
    int i = blockIdx.x * blockDim.x + threadIdx.x;
    float p0 = 0.f, p1 = 0.f, p2 = 0.f;
    if (i < N) {
        float s0 = h3p[3*i], s1 = h3p[3*i+1], s2 = h3p[3*i+2];
        int beg = offs[i], end = offs[i+1];
        for (int k = beg; k < end; ++k) {
            int s = col[k];
            s0 += h3p[3*s]; s1 += h3p[3*s+1]; s2 += h3p[3*s+2];
        }
        float di = dinv[i];
        float t0 = s0 * di + b3[0];
        float t1 = s1 * di + b3[1];
        float t2 = s2 * di + b3[2];
        p0 = t0*Wp[0] + t1*Wp[3] + t2*Wp[6] + bp[0];
        p1 = t0*Wp[1] + t1*Wp[4] + t2*Wp[7] + bp[1];
        p2 = t0*Wp[2] + t1*Wp[5] + t2*Wp[8] + bp[2];
        hout[3*i] = p0; hout[3*i+1] = p1; hout[3*i+2] = p2;
    }
    #pragma unroll
    for (int off = 32; off > 0; off >>= 1) {
        p0 += __shfl_down(p0, off);
        p1 += __shfl_down(p1, off);
        p2 += __shfl_down(p2, off);
    }
    if ((threadIdx.x & 63) == 0) {
        atomicAdd(&gsum[0], p0);
        atomicAdd(&gsum[1], p1);
        atomicAdd(&gsum[2], p2);
    }
}

// ---- head: mean, logits, log_softmax
__global__ void k_head(const float* __restrict__ gsum, const float* __restrict__ Wl,
                       const float* __restrict__ bl, float* __restrict__ out, int N) {
    if (blockIdx.x != 0 || threadIdx.x != 0) return;
    float p0 = gsum[0] / (float)N, p1 = gsum[1] / (float)N, p2 = gsum[2] / (float)N;
    float l[10];
    float m = -1e30f;
    #pragma unroll
    for (int j = 0; j < 10; ++j) {
        l[j] = p0 * Wl[j] + p1 * Wl[10 + j] + p2 * Wl[20 + j] + bl[j];
        m = fmaxf(m, l[j]);
    }
    float s = 0.f;
    #pragma unroll
    for (int j = 0; j < 10; ++j) s += expf(l[j] - m);
    float lse = logf(s) + m;
    #pragma unroll
    for (int j = 0; j < 10; ++j) out[j] = l[j] - lse;
}

extern "C" void kernel_launch(void* const* d_in, const int* in_sizes, int n_in,
                              void* d_out, int out_size, void* d_ws, size_t ws_size,
                              hipStream_t stream) {
    const int N = N_NODES;
    const float* x  = (const float*)d_in[0];
    const int*   ei = (const int*)d_in[1];
    const int    E  = in_sizes[1] / 2;
    const int* src = ei;
    const int* dst = ei + E;
    const float* W1 = (const float*)d_in[2];
    const float* b1 = (const float*)d_in[3];
    const float* W2 = (const float*)d_in[4];
    const float* b2 = (const float*)d_in[5];
    const float* W3 = (const float*)d_in[6];
    const float* b3 = (const float*)d_in[7];
    const float* Wp = (const float*)d_in[8];
    const float* bp = (const float*)d_in[9];
    const float* Wl = (const float*)d_in[10];
    const float* bl = (const float*)d_in[11];

    float* out     = (float*)d_out;
    float* h_out   = out + 10;              // [N,3]
    float* emb_out = out + 10 + 3 * N;      // [N,3]

    // ---- workspace layout (4-byte units) ----
    char* W = (char*)d_ws;
    size_t off = 0;
    auto alloc = [&](size_t elems) { void* p = W + off; off += elems * 4; return p; };

    int*   col  = (int*)alloc((size_t)E);
    int*   deg  = (int*)alloc(N);
    int*   offs = (int*)alloc(N + 1);
    float* dinv = (float*)alloc(N);
    float* bufA = (float*)alloc(3 * N);
    float* bufB = (float*)alloc(3 * N);
    float* gsum = (float*)alloc(4);
    int*   part = (int*)alloc(1024);
    size_t base_bytes = off;
    size_t rank_bytes = base_bytes + (size_t)E * 4;
    bool use_rank = (ws_size >= rank_bytes);
    int* rank = (int*)(W + base_bytes);              // rank path (E ints)
    int* cur  = (int*)(W + base_bytes);              // cursor path (N ints)

    hipMemsetAsync(deg, 0, N * sizeof(int), stream);
    hipMemsetAsync(gsum, 0, 4 * sizeof(float), stream);
    if (!use_rank) hipMemsetAsync(cur, 0, N * sizeof(int), stream);

    const int B = 256;
    int gE = (E + B - 1) / B;
    int gN = (N + B - 1) / B;   // 391 blocks <= 1024

    // CSR build
    if (use_rank) {
        k_rank<<<gE, B, 0, stream>>>(dst, E, deg, rank);
    } else {
        k_deg<<<gE, B, 0, stream>>>(dst, E, deg);
    }
    k_scan1<<<gN, B, 0, stream>>>(deg, offs, dinv, part, N);
    k_scan2<<<1, 1024, 0, stream>>>(part, offs, gN, N);
    k_scan3<<<gN, B, 0, stream>>>(offs, part, N);
    if (use_rank) {
        k_fill_rank<<<gE, B, 0, stream>>>(src, dst, rank, offs, col, E);
    } else {
        k_fill_cur<<<gE, B, 0, stream>>>(src, dst, offs, cur, col, E);
    }

    // convs (all 3-wide thanks to Â(xW) = (Âx)W)
    k_prescale<<<gN, B, 0, stream>>>(x, dinv, bufA, N);
    k_conv1<<<gN, B, 0, stream>>>(offs, col, bufA, dinv, W1, b1, W2, bufB, N);
    k_conv2<<<gN, B, 0, stream>>>(offs, col, bufB, dinv, b2, W3, emb_out, bufA, N);
    k_conv3<<<gN, B, 0, stream>>>(offs, col, bufA, dinv, b3, Wp, bp, h_out, gsum, N);

    k_head<<<1, 64, 0, stream>>>(gsum, Wl, bl, out, N);
}

// Round 4
// 255.595 us; speedup vs baseline: 2.8762x; 1.3792x over previous
//
#include <hip/hip_runtime.h>
#include <math.h>

#define N_NODES 100000
#define NB 256          // partition blocks
#define NP 1024         // buckets (dst >> 7), only first 782 non-empty

// ================= bucket-path CSR build (no global atomics) =================

// per-block LDS histogram over buckets -> hist[block*NP + bucket]
__global__ void k_hist(const int* __restrict__ dst, int E, int chunk,
                       int* __restrict__ hist) {
    __shared__ int bin[NP];
    for (int i = threadIdx.x; i < NP; i += 256) bin[i] = 0;
    __syncthreads();
    int beg = blockIdx.x * chunk;
    int end = beg + chunk; if (end > E) end = E;
    for (int e = beg + threadIdx.x; e < end; e += 256)
        atomicAdd(&bin[dst[e] >> 7], 1);
    __syncthreads();
    for (int i = threadIdx.x; i < NP; i += 256)
        hist[blockIdx.x * NP + i] = bin[i];
}

// bucket totals + exclusive scan -> base[0..NP], base[NP]=E   (1 block x 1024)
__global__ void k_s1(const int* __restrict__ hist, int* __restrict__ base) {
    __shared__ int sh[NP];
    int b = threadIdx.x;
    int s = 0;
    #pragma unroll 8
    for (int k = 0; k < NB; ++k) s += hist[k * NP + b];
    sh[b] = s;
    __syncthreads();
    for (int off = 1; off < NP; off <<= 1) {
        int u = (b >= off) ? sh[b - off] : 0;
        __syncthreads();
        sh[b] += u;
        __syncthreads();
    }
    base[b] = sh[b] - s;               // exclusive
    if (b == NP - 1) base[NP] = sh[b];
}

// per-bucket scan over block counts: hist[k][b] := base[b] + sum_{k'<k} hist[k'][b]
__global__ void k_s2(int* __restrict__ hist, const int* __restrict__ base) {
    __shared__ int sh[NB];
    int b = blockIdx.x, t = threadIdx.x;   // t == block index k
    int v = hist[t * NP + b];
    sh[t] = v;
    __syncthreads();
    for (int off = 1; off < NB; off <<= 1) {
        int u = (t >= off) ? sh[t - off] : 0;
        __syncthreads();
        sh[t] += u;
        __syncthreads();
    }
    hist[t * NP + b] = base[b] + sh[t] - v;
}

// partition edges into bucket-grouped part[]: value = (src<<7) | (dst&127)
__global__ void k_part(const int* __restrict__ src, const int* __restrict__ dst,
                       int E, int chunk, const int* __restrict__ hist,
                       unsigned int* __restrict__ part) {
    __shared__ int cur[NP];
    for (int i = threadIdx.x; i < NP; i += 256)
        cur[i] = hist[blockIdx.x * NP + i];
    __syncthreads();
    int beg = blockIdx.x * chunk;
    int end = beg + chunk; if (end > E) end = E;
    for (int e = beg + threadIdx.x; e < end; e += 256) {
        int d = dst[e];
        int p = atomicAdd(&cur[d >> 7], 1);
        part[p] = ((unsigned)src[e] << 7) | (unsigned)(d & 127);
    }
}

// per-bucket: deg count -> dinv + offs + prescaled xp; local scatter -> col
__global__ void k_csr(const unsigned int* __restrict__ part, const int* __restrict__ base,
                      const float* __restrict__ x,
                      float* __restrict__ dinv, int* __restrict__ offs,
                      float* __restrict__ xp, int* __restrict__ col, int N) {
    __shared__ int cnt[128];
    __shared__ int scn[128];
    __shared__ int cur[128];
    int b = blockIdx.x, t = threadIdx.x;
    int lo = base[b], hi = base[b + 1];
    if (t < 128) cnt[t] = 0;
    __syncthreads();
    for (int e = lo + t; e < hi; e += 256)
        atomicAdd(&cnt[part[e] & 127u], 1);
    __syncthreads();
    int v = (t < 128) ? cnt[t] : 0;
    if (t < 128) scn[t] = v;
    __syncthreads();
    for (int off = 1; off < 128; off <<= 1) {
        int u = (t < 128 && t >= off) ? scn[t - off] : 0;
        __syncthreads();
        if (t < 128) scn[t] += u;
        __syncthreads();
    }
    if (t < 128) {
        int pos = lo + scn[t] - v;      // exclusive
        cur[t] = pos;
        int g = (b << 7) + t;
        if (g < N) {
            offs[g] = pos;
            float di = rsqrtf((float)(v + 1));   // +1 self-loop
            dinv[g] = di;
            xp[3*g]   = x[3*g]   * di;
            xp[3*g+1] = x[3*g+1] * di;
            xp[3*g+2] = x[3*g+2] * di;
        }
    }
    if (b == 0 && t == 0) offs[N] = base[(N_NODES + 127) >> 7];
    __syncthreads();
    for (int e = lo + t; e < hi; e += 256) {
        unsigned int w = part[e];
        int p = atomicAdd(&cur[w & 127u], 1);
        col[p] = (int)(w >> 7);
    }
}

// ================= fallback CSR build (global atomics, R3 pipeline) ==========

__global__ void k_deg(const int* __restrict__ dst, int E, int* __restrict__ deg) {
    int e = blockIdx.x * blockDim.x + threadIdx.x;
    if (e < E) atomicAdd(&deg[dst[e]], 1);
}

__global__ void k_scan1(const int* __restrict__ deg, int* __restrict__ offs,
                        float* __restrict__ dinv, int* __restrict__ partl, int N) {
    __shared__ int sh[256];
    int i = blockIdx.x * 256 + threadIdx.x;
    int t = threadIdx.x;
    int v = (i < N) ? deg[i] : 0;
    sh[t] = v;
    __syncthreads();
    #pragma unroll
    for (int off = 1; off < 256; off <<= 1) {
        int u = (t >= off) ? sh[t - off] : 0;
        __syncthreads();
        sh[t] += u;
        __syncthreads();
    }
    if (i < N) {
        offs[i] = sh[t] - v;
        dinv[i] = rsqrtf((float)(v + 1));
    }
    if (t == 255) partl[blockIdx.x] = sh[255];
}

__global__ void k_scan2(int* __restrict__ partl, int* __restrict__ offs, int nb, int N) {
    __shared__ int sh[1024];
    int t = threadIdx.x;
    int v = (t < nb) ? partl[t] : 0;
    sh[t] = v;
    __syncthreads();
    #pragma unroll
    for (int off = 1; off < 1024; off <<= 1) {
        int u = (t >= off) ? sh[t - off] : 0;
        __syncthreads();
        sh[t] += u;
        __syncthreads();
    }
    if (t < nb) partl[t] = sh[t] - v;
    if (t == 1023) offs[N] = sh[1023];
}

__global__ void k_scan3(int* __restrict__ offs, const int* __restrict__ partl, int N) {
    int i = blockIdx.x * 256 + threadIdx.x;
    if (i < N) offs[i] += partl[blockIdx.x];
}

__global__ void k_fill_cur(const int* __restrict__ src, const int* __restrict__ dst,
                           const int* __restrict__ offs, int* __restrict__ cur,
                           int* __restrict__ col, int E) {
    int e = blockIdx.x * blockDim.x + threadIdx.x;
    if (e >= E) return;
    int d = dst[e];
    col[offs[d] + atomicAdd(&cur[d], 1)] = src[e];
}

__global__ void k_prescale(const float* __restrict__ x, const float* __restrict__ dinv,
                           float* __restrict__ xp, int N) {
    int i = blockIdx.x * blockDim.x + threadIdx.x;
    if (i >= N) return;
    float di = dinv[i];
    xp[3*i]   = x[3*i]   * di;
    xp[3*i+1] = x[3*i+1] * di;
    xp[3*i+2] = x[3*i+2] * di;
}

// ================= convs (unchanged from R3) =================

__global__ void k_conv1(const int* __restrict__ offs, const int* __restrict__ col,
                        const float* __restrict__ xp, const float* __restrict__ dinv,
                        const float* __restrict__ W1, const float* __restrict__ b1,
                        const float* __restrict__ W2,
                        float* __restrict__ h2p, int N) {
    int i = blockIdx.x * blockDim.x + threadIdx.x;
    if (i >= N) return;
    float s0 = xp[3*i], s1 = xp[3*i+1], s2 = xp[3*i+2];  // self-loop term
    int beg = offs[i], end = offs[i+1];
    for (int k = beg; k < end; ++k) {
        int s = col[k];
        s0 += xp[3*s]; s1 += xp[3*s+1]; s2 += xp[3*s+2];
    }
    float di = dinv[i];
    float g0 = s0 * di, g1 = s1 * di, g2 = s2 * di;
    float o0 = 0.f, o1 = 0.f, o2 = 0.f;
    #pragma unroll
    for (int j = 0; j < 16; ++j) {
        float t = fmaxf(g0 * W1[j] + g1 * W1[16 + j] + g2 * W1[32 + j] + b1[j], 0.f);
        o0 += t * W2[3*j + 0];
        o1 += t * W2[3*j + 1];
        o2 += t * W2[3*j + 2];
    }
    h2p[3*i] = o0 * di; h2p[3*i+1] = o1 * di; h2p[3*i+2] = o2 * di;
}

__global__ void k_conv2(const int* __restrict__ offs, const int* __restrict__ col,
                        const float* __restrict__ h2p, const float* __restrict__ dinv,
                        const float* __restrict__ b2, const float* __restrict__ W3,
                        float* __restrict__ embed_out, float* __restrict__ h3p, int N) {
    int i = blockIdx.x * blockDim.x + threadIdx.x;
    if (i >= N) return;
    float s0 = h2p[3*i], s1 = h2p[3*i+1], s2 = h2p[3*i+2];
    int beg = offs[i], end = offs[i+1];
    for (int k = beg; k < end; ++k) {
        int s = col[k];
        s0 += h2p[3*s]; s1 += h2p[3*s+1]; s2 += h2p[3*s+2];
    }
    float di = dinv[i];
    float t0 = s0 * di + b2[0];
    float t1 = s1 * di + b2[1];
    float t2 = s2 * di + b2[2];
    float inv = 1.0f / fmaxf(sqrtf(t0*t0 + t1*t1 + t2*t2), 1e-12f);
    float e0 = t0*inv, e1 = t1*inv, e2 = t2*inv;
    embed_out[3*i] = e0; embed_out[3*i+1] = e1; embed_out[3*i+2] = e2;
    h3p[3*i]   = (e0*W3[0] + e1*W3[3] + e2*W3[6]) * di;
    h3p[3*i+1] = (e0*W3[1] + e1*W3[4] + e2*W3[7]) * di;
    h3p[3*i+2] = (e0*W3[2] + e1*W3[5] + e2*W3[8]) * di;
}

__global__ void k_conv3(const int* __restrict__ offs, const int* __restrict__ col,
                        const float* __restrict__ h3p, const float* __restrict__ dinv,
                        const float* __restrict__ b3, const float* __restrict__ Wp,
                        const float* __restrict__ bp,
                        float* __restrict__ hout, float* __restrict__ gsum, int N) {
    int i = blockIdx.x * blockDim.x + threadIdx.x;
    float p0 = 0.f, p1 = 0.f, p2 = 0.f;
    if (i < N) {
        float s0 = h3p[3*i], s1 = h3p[3*i+1], s2 = h3p[3*i+2];
        int beg = offs[i], end = offs[i+1];
        for (int k = beg; k < end; ++k) {
            int s = col[k];
            s0 += h3p[3*s]; s1 += h3p[3*s+1]; s2 += h3p[3*s+2];
        }
        float di = dinv[i];
        float t0 = s0 * di + b3[0];
        float t1 = s1 * di + b3[1];
        float t2 = s2 * di + b3[2];
        p0 = t0*Wp[0] + t1*Wp[3] + t2*Wp[6] + bp[0];
        p1 = t0*Wp[1] + t1*Wp[4] + t2*Wp[7] + bp[1];
        p2 = t0*Wp[2] + t1*Wp[5] + t2*Wp[8] + bp[2];
        hout[3*i] = p0; hout[3*i+1] = p1; hout[3*i+2] = p2;
    }
    #pragma unroll
    for (int off = 32; off > 0; off >>= 1) {
        p0 += __shfl_down(p0, off);
        p1 += __shfl_down(p1, off);
        p2 += __shfl_down(p2, off);
    }
    if ((threadIdx.x & 63) == 0) {
        atomicAdd(&gsum[0], p0);
        atomicAdd(&gsum[1], p1);
        atomicAdd(&gsum[2], p2);
    }
}

__global__ void k_head(const float* __restrict__ gsum, const float* __restrict__ Wl,
                       const float* __restrict__ bl, float* __restrict__ out, int N) {
    if (blockIdx.x != 0 || threadIdx.x != 0) return;
    float p0 = gsum[0] / (float)N, p1 = gsum[1] / (float)N, p2 = gsum[2] / (float)N;
    float l[10];
    float m = -1e30f;
    #pragma unroll
    for (int j = 0; j < 10; ++j) {
        l[j] = p0 * Wl[j] + p1 * Wl[10 + j] + p2 * Wl[20 + j] + bl[j];
        m = fmaxf(m, l[j]);
    }
    float s = 0.f;
    #pragma unroll
    for (int j = 0; j < 10; ++j) s += expf(l[j] - m);
    float lse = logf(s) + m;
    #pragma unroll
    for (int j = 0; j < 10; ++j) out[j] = l[j] - lse;
}

extern "C" void kernel_launch(void* const* d_in, const int* in_sizes, int n_in,
                              void* d_out, int out_size, void* d_ws, size_t ws_size,
                              hipStream_t stream) {
    const int N = N_NODES;
    const float* x  = (const float*)d_in[0];
    const int*   ei = (const int*)d_in[1];
    const int    E  = in_sizes[1] / 2;
    const int* src = ei;
    const int* dst = ei + E;
    const float* W1 = (const float*)d_in[2];
    const float* b1 = (const float*)d_in[3];
    const float* W2 = (const float*)d_in[4];
    const float* b2 = (const float*)d_in[5];
    const float* W3 = (const float*)d_in[6];
    const float* b3 = (const float*)d_in[7];
    const float* Wp = (const float*)d_in[8];
    const float* bp = (const float*)d_in[9];
    const float* Wl = (const float*)d_in[10];
    const float* bl = (const float*)d_in[11];

    float* out     = (float*)d_out;
    float* h_out   = out + 10;              // [N,3]
    float* emb_out = out + 10 + 3 * N;      // [N,3]

    const int B = 256;
    int gE = (E + B - 1) / B;
    int gN = (N + B - 1) / B;
    int chunk = (E + NB - 1) / NB;
    int PB = (N + 127) >> 7;               // 782 non-empty buckets

    char* Wm = (char*)d_ws;

    // ---- bucket-path layout ----
    size_t off = 0;
    auto alloc = [&](size_t elems) { void* p = Wm + off; off += elems * 4; return p; };
    int*          col  = (int*)alloc((size_t)E);
    unsigned int* part = (unsigned int*)alloc((size_t)E);
    int*          hist = (int*)alloc((size_t)NB * NP);
    int*          base = (int*)alloc(NP + 1);
    float*        dinv = (float*)alloc(N);
    int*          offs = (int*)alloc(N + 1);
    float*        bufA = (float*)alloc(3 * N);
    float*        bufB = (float*)alloc(3 * N);
    float*        gsum = (float*)alloc(4);
    size_t need_bucket = off;

    if (ws_size >= need_bucket) {
        hipMemsetAsync(gsum, 0, 4 * sizeof(float), stream);
        k_hist<<<NB, B, 0, stream>>>(dst, E, chunk, hist);
        k_s1<<<1, NP, 0, stream>>>(hist, base);
        k_s2<<<NP, NB, 0, stream>>>(hist, base);
        k_part<<<NB, B, 0, stream>>>(src, dst, E, chunk, hist, part);
        k_csr<<<PB, B, 0, stream>>>(part, base, x, dinv, offs, bufA, col, N);
    } else {
        // ---- fallback layout (R3 cursor pipeline) ----
        off = 0;
        col  = (int*)alloc((size_t)E);
        int* deg = (int*)alloc(N);
        offs = (int*)alloc(N + 1);
        dinv = (float*)alloc(N);
        bufA = (float*)alloc(3 * N);
        bufB = (float*)alloc(3 * N);
        gsum = (float*)alloc(4);
        int* partl = (int*)alloc(1024);
        int* cur = (int*)alloc(N);

        hipMemsetAsync(deg, 0, N * sizeof(int), stream);
        hipMemsetAsync(gsum, 0, 4 * sizeof(float), stream);
        hipMemsetAsync(cur, 0, N * sizeof(int), stream);

        k_deg<<<gE, B, 0, stream>>>(dst, E, deg);
        k_scan1<<<gN, B, 0, stream>>>(deg, offs, dinv, partl, N);
        k_scan2<<<1, 1024, 0, stream>>>(partl, offs, gN, N);
        k_scan3<<<gN, B, 0, stream>>>(offs, partl, N);
        k_fill_cur<<<gE, B, 0, stream>>>(src, dst, offs, cur, col, E);
        k_prescale<<<gN, B, 0, stream>>>(x, dinv, bufA, N);
    }

    // convs (shared)
    k_conv1<<<gN, B, 0, stream>>>(offs, col, bufA, dinv, W1, b1, W2, bufB, N);
    k_conv2<<<gN, B, 0, stream>>>(offs, col, bufB, dinv, b2, W3, emb_out, bufA, N);
    k_conv3<<<gN, B, 0, stream>>>(offs, col, bufA, dinv, b3, Wp, bp, h_out, gsum, N);

    k_head<<<1, 64, 0, stream>>>(gsum, Wl, bl, out, N);
}